// Round 5
// baseline (258.300 us; speedup 1.0000x reference)
//
#include <hip/hip_runtime.h>

typedef __attribute__((ext_vector_type(8))) short short8;
typedef __attribute__((ext_vector_type(4))) float f32x4;

// Problem dims
#define BDIM 4096
#define INDIM 1024
#define HDIM 2048
#define KDIM 3072   // IN + H
#define NDIM 8192   // 4*H
#define OUT_HALF 8388608  // 4096*2048
#define NKT 96      // K-tiles of 32
#define BUFB 24576  // ring buffer bytes: A[128][32]sw 8K + B[256][32]sw 16K

__device__ __forceinline__ unsigned short f2bf(float f) {
  unsigned u = __float_as_uint(f);
  u += 0x7FFFu + ((u >> 16) & 1u);
  return (unsigned short)(u >> 16);
}

__device__ __forceinline__ float sigmoidf_(float x) {
  return 1.0f / (1.0f + __expf(-x));
}

// Pack A = [x | h] as bf16, row-major [4096][3072]
__global__ __launch_bounds__(256) void pack_a(const float* __restrict__ x,
                                              const float* __restrict__ hh,
                                              unsigned short* __restrict__ A) {
  int idx = blockIdx.x * 256 + threadIdx.x;
  int m = idx / 384;
  int k0 = (idx - m * 384) * 8;
  const float* src = (k0 < INDIM) ? (x + (size_t)m * INDIM + k0)
                                  : (hh + (size_t)m * HDIM + (k0 - INDIM));
  float4 lo = ((const float4*)src)[0];
  float4 hi = ((const float4*)src)[1];
  union { unsigned short us[8]; uint4 v; } o;
  o.us[0] = f2bf(lo.x); o.us[1] = f2bf(lo.y); o.us[2] = f2bf(lo.z); o.us[3] = f2bf(lo.w);
  o.us[4] = f2bf(hi.x); o.us[5] = f2bf(hi.y); o.us[6] = f2bf(hi.z); o.us[7] = f2bf(hi.w);
  *(uint4*)(A + (size_t)m * KDIM + k0) = o.v;
}

// Pack W' (gate-interleaved rows) as bf16 [8192][3072]; W'[4*j+g] = [w_ih|w_hh][g*2048+j]
__global__ __launch_bounds__(256) void pack_w(const float* __restrict__ w_ih,
                                              const float* __restrict__ w_hh,
                                              const float* __restrict__ b_ih,
                                              const float* __restrict__ b_hh,
                                              unsigned short* __restrict__ W,
                                              float* __restrict__ bias) {
  int idx = blockIdx.x * 256 + threadIdx.x;
  int np = idx / 384;
  int rem = idx - np * 384;
  int k0 = rem * 8;
  int j = np >> 2;
  int g = np & 3;
  int n = g * HDIM + j;
  const float* src = (k0 < INDIM) ? (w_ih + (size_t)n * INDIM + k0)
                                  : (w_hh + (size_t)n * HDIM + (k0 - INDIM));
  float4 lo = ((const float4*)src)[0];
  float4 hi = ((const float4*)src)[1];
  union { unsigned short us[8]; uint4 v; } o;
  o.us[0] = f2bf(lo.x); o.us[1] = f2bf(lo.y); o.us[2] = f2bf(lo.z); o.us[3] = f2bf(lo.w);
  o.us[4] = f2bf(hi.x); o.us[5] = f2bf(hi.y); o.us[6] = f2bf(hi.z); o.us[7] = f2bf(hi.w);
  *(uint4*)(W + (size_t)np * KDIM + k0) = o.v;
  if (rem == 0) bias[np] = b_ih[n] + b_hh[n];
}

__device__ __forceinline__ void gload_lds16(const void* g, void* l) {
  __builtin_amdgcn_global_load_lds(
      (const __attribute__((address_space(1))) void*)g,
      (__attribute__((address_space(3))) void*)l, 16, 0, 0);
}

#define SB0 __builtin_amdgcn_sched_barrier(0)

// 128x256 tile, BK=32, 4 waves (1Mx4N), 256 threads, ring-3 LDS (72 KiB)
// -> 2 independent blocks/CU. Row-pair XOR swizzle (T2), counted vmcnt (T4),
// setprio (T5), 1-phase-ahead ds_read prefetch (T3).
__global__ __launch_bounds__(256, 2) void lstm_gemm(
    const unsigned short* __restrict__ A,
    const unsigned short* __restrict__ W,
    const float* __restrict__ bias,
    const float* __restrict__ c,
    float* __restrict__ out) {
  extern __shared__ char smem[];  // 73728 bytes

  const int tid = threadIdx.x;
  const int lane = tid & 63;
  const int wid = tid >> 6;   // 0..3 (wave col)

  // XCD swizzle: xcd owns 4 tn-tiles (W slab 1.5MB L2-resident), tm fast.
  const int bid = blockIdx.x;              // 1024 blocks
  const int local = bid >> 3;              // 0..127
  const int tn = (bid & 7) * 4 + (local >> 5);  // 0..31
  const int tm = local & 31;                    // 0..31

  // ---- staging source decode (inverse swizzle, rule #21) ----
  // Round q (A: q=0,1; B: q=0..3): region-local P = q*4096 + wid*1024 + lane*16
  int rowQ[4], colQ[4];
#pragma unroll
  for (int q = 0; q < 4; ++q) {
    int P = q * 4096 + wid * 1024 + lane * 16;
    int r2 = P >> 7, cp = (P >> 4) & 7, cg = cp ^ (r2 & 7);
    rowQ[q] = r2 * 2 + (cg >> 2);
    colQ[q] = (cg & 3) * 8;
  }
  const unsigned short* sA0 = A + (size_t)(tm * 128 + rowQ[0]) * KDIM + colQ[0];
  const unsigned short* sA1 = A + (size_t)(tm * 128 + rowQ[1]) * KDIM + colQ[1];
  const unsigned short* sB0 = W + (size_t)(tn * 256 + rowQ[0]) * KDIM + colQ[0];
  const unsigned short* sB1 = W + (size_t)(tn * 256 + rowQ[1]) * KDIM + colQ[1];
  const unsigned short* sB2 = W + (size_t)(tn * 256 + rowQ[2]) * KDIM + colQ[2];
  const unsigned short* sB3 = W + (size_t)(tn * 256 + rowQ[3]) * KDIM + colQ[3];
  const int dA0 = wid * 1024;
  const int dA1 = 4096 + wid * 1024;
  const int dB0 = 8192 + wid * 1024;
  const int dB1 = 12288 + wid * 1024;
  const int dB2 = 16384 + wid * 1024;
  const int dB3 = 20480 + wid * 1024;

  // ---- ds_read per-lane constants (swizzled) ----
  const int fr = lane & 15;
  const int fq = lane >> 4;
  const int frh = fr >> 1;
  const int clA = (((fr & 1) << 2) | fq) ^ frh;
  const int aconst = frh * 128 + clA * 16;                       // + mi*1024
  const int bconst = 8192 + wid * 4096 + frh * 128 + clA * 16;   // + ni*1024

  f32x4 acc[8][4] = {};
  short8 af[4], bf_[4], ag[4];

  char* b0 = smem;
  char* b1 = smem + BUFB;
  char* b2 = smem + 2 * BUFB;

#define STAGE_TILE(K, LB)                                   \
  do {                                                      \
    gload_lds16(sA0 + (size_t)(K) * 32, (LB) + dA0);        \
    gload_lds16(sA1 + (size_t)(K) * 32, (LB) + dA1);        \
    gload_lds16(sB0 + (size_t)(K) * 32, (LB) + dB0);        \
    gload_lds16(sB1 + (size_t)(K) * 32, (LB) + dB1);        \
    gload_lds16(sB2 + (size_t)(K) * 32, (LB) + dB2);        \
    gload_lds16(sB3 + (size_t)(K) * 32, (LB) + dB3);        \
  } while (0)

  // ---- prologue: stage tiles 0,1 ----
  STAGE_TILE(0, b0);
  STAGE_TILE(1, b1);
  asm volatile("s_waitcnt vmcnt(6)" ::: "memory");   // tile 0 landed
  __builtin_amdgcn_s_barrier(); SB0;
#pragma unroll
  for (int mi = 0; mi < 4; ++mi)
    af[mi] = *(const short8*)(b0 + aconst + mi * 1024);
#pragma unroll
  for (int ni = 0; ni < 4; ++ni)
    bf_[ni] = *(const short8*)(b0 + bconst + ni * 1024);

// Body. Entry: af(T),bf_(T) issued; ring holds T(RB),T+1(RBN ready/landing).
#define BODY(T, RB, RBN, LB, VMSTR, STG, STAGE_, PREF_)                      \
  do {                                                                       \
    if (STAGE_) {                                                            \
      gload_lds16(sA0 + (size_t)(STG) * 32, (LB) + dA0);                     \
      gload_lds16(sA1 + (size_t)(STG) * 32, (LB) + dA1);                     \
    }                                                                        \
    _Pragma("unroll")                                                        \
    for (int mi = 0; mi < 4; ++mi)                                           \
      ag[mi] = *(const short8*)((RB) + aconst + (mi + 4) * 1024);            \
    SB0;                                                                     \
    __builtin_amdgcn_s_setprio(1);                                           \
    _Pragma("unroll")                                                        \
    for (int mi = 0; mi < 4; ++mi)                                           \
      _Pragma("unroll")                                                      \
      for (int ni = 0; ni < 4; ++ni)                                         \
        acc[mi][ni] = __builtin_amdgcn_mfma_f32_16x16x32_bf16(               \
            af[mi], bf_[ni], acc[mi][ni], 0, 0, 0);                          \
    __builtin_amdgcn_s_setprio(0);                                           \
    if (STAGE_) {                                                            \
      gload_lds16(sB0 + (size_t)(STG) * 32, (LB) + dB0);                     \
      gload_lds16(sB1 + (size_t)(STG) * 32, (LB) + dB1);                     \
      gload_lds16(sB2 + (size_t)(STG) * 32, (LB) + dB2);                     \
      gload_lds16(sB3 + (size_t)(STG) * 32, (LB) + dB3);                     \
    }                                                                        \
    asm volatile("s_waitcnt vmcnt(" VMSTR ")" ::: "memory");                 \
    asm volatile("s_waitcnt lgkmcnt(0)" ::: "memory");                       \
    __builtin_amdgcn_s_barrier(); SB0;                                       \
    if (PREF_) {                                                             \
      _Pragma("unroll")                                                      \
      for (int mi = 0; mi < 4; ++mi)                                         \
        af[mi] = *(const short8*)((RBN) + aconst + mi * 1024);               \
    }                                                                        \
    SB0;                                                                     \
    __builtin_amdgcn_s_setprio(1);                                           \
    _Pragma("unroll")                                                        \
    for (int mi = 0; mi < 4; ++mi)                                           \
      _Pragma("unroll")                                                      \
      for (int ni = 0; ni < 4; ++ni)                                         \
        acc[mi + 4][ni] = __builtin_amdgcn_mfma_f32_16x16x32_bf16(           \
            ag[mi], bf_[ni], acc[mi + 4][ni], 0, 0, 0);                      \
    __builtin_amdgcn_s_setprio(0);                                           \
    if (PREF_) {                                                             \
      _Pragma("unroll")                                                      \
      for (int ni = 0; ni < 4; ++ni)                                         \
        bf_[ni] = *(const short8*)((RBN) + bconst + ni * 1024);              \
    }                                                                        \
  } while (0)

  for (int t = 0; t < NKT - 3; t += 3) {
    BODY(t,     b0, b1, b2, "6", t + 2, true, true);
    BODY(t + 1, b1, b2, b0, "6", t + 3, true, true);
    BODY(t + 2, b2, b0, b1, "6", t + 4, true, true);
  }
  BODY(NKT - 3, b0, b1, b2, "6", NKT - 1, true, true);
  BODY(NKT - 2, b1, b2, b0, "0", 0, false, true);
  BODY(NKT - 1, b2, b0, b1, "0", 0, false, false);
#undef BODY
#undef STAGE_TILE

  // ---- fused LSTM epilogue ----
  // Wave owns 128x64 gates. Wave-private LDS bounce, stride 68 floats
  // (16B-aligned rows, 2-way-max banks on writes, uniform on b128 reads).
  const int jw = fr;
  const int jg = tn * 64 + wid * 16 + jw;   // global j in [0,2048)
  const f32x4 bi = *(const f32x4*)(bias + tn * 256 + wid * 64 + jw * 4);
  float* ep = (float*)(smem) + wid * 1152;  // 4608 B per wave

#pragma unroll
  for (int mi = 0; mi < 8; ++mi) {
#pragma unroll
    for (int ni = 0; ni < 4; ++ni)
#pragma unroll
      for (int r = 0; r < 4; ++r)
        ep[(fq * 4 + r) * 68 + ni * 16 + fr] = acc[mi][ni][r];
    asm volatile("s_waitcnt lgkmcnt(0)" ::: "memory");
#pragma unroll
    for (int t4 = 0; t4 < 4; ++t4) {
      const int row = fq + t4 * 4;         // 0..15
      f32x4 g4 = *(const f32x4*)(ep + row * 68 + jw * 4);
      const float f_in = g4[0] + bi[0];
      const float i_in = g4[1] + bi[1];
      const float ic_in = g4[2] + bi[2];
      const float o_in = g4[3] + bi[3];
      const float ft = sigmoidf_(f_in);
      const float it = sigmoidf_(i_in);
      const float ics = __sinf(ic_in);
      const int mg = tm * 128 + mi * 16 + row;
      const float cv = c[(size_t)mg * HDIM + jg];
      const float ct = cv * ft + ics * it;
      const float ot = sigmoidf_(o_in);
      const float ht = ot * __sinf(ct);
      out[(size_t)mg * HDIM + jg] = ht;
      out[OUT_HALF + (size_t)mg * HDIM + jg] = ct;
    }
    asm volatile("s_waitcnt lgkmcnt(0)" ::: "memory");
  }
}

extern "C" void kernel_launch(void* const* d_in, const int* in_sizes, int n_in,
                              void* d_out, int out_size, void* d_ws, size_t ws_size,
                              hipStream_t stream) {
  const float* x    = (const float*)d_in[0];
  const float* h    = (const float*)d_in[1];
  const float* c    = (const float*)d_in[2];
  const float* w_ih = (const float*)d_in[3];
  const float* w_hh = (const float*)d_in[4];
  const float* b_ih = (const float*)d_in[5];
  const float* b_hh = (const float*)d_in[6];
  float* out = (float*)d_out;

  char* ws = (char*)d_ws;
  unsigned short* Abf = (unsigned short*)ws;                       // 25,165,824 B
  unsigned short* Wbf = (unsigned short*)(ws + 25165824);          // 50,331,648 B
  float* bias = (float*)(ws + 25165824 + 50331648);                // 32,768 B

  hipFuncSetAttribute((const void*)lstm_gemm,
                      hipFuncAttributeMaxDynamicSharedMemorySize, 73728);

  pack_a<<<6144, 256, 0, stream>>>(x, h, Abf);
  pack_w<<<12288, 256, 0, stream>>>(w_ih, w_hh, b_ih, b_hh, Wbf, bias);
  lstm_gemm<<<1024, 256, 73728, stream>>>(Abf, Wbf, bias, c, out);
}

// Round 6
// 221.427 us; speedup vs baseline: 1.1665x; 1.1665x over previous
//
#include <hip/hip_runtime.h>

typedef __attribute__((ext_vector_type(8))) short short8;
typedef __attribute__((ext_vector_type(4))) float f32x4;

// Problem dims
#define BDIM 4096
#define INDIM 1024
#define HDIM 2048
#define KDIM 3072   // IN + H
#define NDIM 8192   // 4*H
#define OUT_HALF 8388608  // 4096*2048
#define NKT 48      // K-tiles of 64
#define ACHUNKS 1572864

__device__ __forceinline__ unsigned short f2bf(float f) {
  unsigned u = __float_as_uint(f);
  u += 0x7FFFu + ((u >> 16) & 1u);
  return (unsigned short)(u >> 16);
}

__device__ __forceinline__ float sigmoidf_(float x) {
  return 1.0f / (1.0f + __expf(-x));
}

// Merged pack: A = [x|h] bf16 [4096][3072]; W' gate-interleaved bf16 [8192][3072];
// bias[n'] = b_ih + b_hh.
__global__ __launch_bounds__(256) void pack_all(
    const float* __restrict__ x, const float* __restrict__ hh,
    const float* __restrict__ w_ih, const float* __restrict__ w_hh,
    const float* __restrict__ b_ih, const float* __restrict__ b_hh,
    unsigned short* __restrict__ A, unsigned short* __restrict__ W,
    float* __restrict__ bias) {
  int idx = blockIdx.x * 256 + threadIdx.x;
  if (idx < ACHUNKS) {
    int m = idx / 384;
    int k0 = (idx - m * 384) * 8;
    const float* src = (k0 < INDIM) ? (x + (size_t)m * INDIM + k0)
                                    : (hh + (size_t)m * HDIM + (k0 - INDIM));
    float4 lo = ((const float4*)src)[0];
    float4 hi = ((const float4*)src)[1];
    union { unsigned short us[8]; uint4 v; } o;
    o.us[0] = f2bf(lo.x); o.us[1] = f2bf(lo.y); o.us[2] = f2bf(lo.z); o.us[3] = f2bf(lo.w);
    o.us[4] = f2bf(hi.x); o.us[5] = f2bf(hi.y); o.us[6] = f2bf(hi.z); o.us[7] = f2bf(hi.w);
    *(uint4*)(A + (size_t)m * KDIM + k0) = o.v;
  } else {
    idx -= ACHUNKS;
    int np = idx / 384;
    int rem = idx - np * 384;
    int k0 = rem * 8;
    int j = np >> 2;
    int g = np & 3;
    int n = g * HDIM + j;
    const float* src = (k0 < INDIM) ? (w_ih + (size_t)n * INDIM + k0)
                                    : (w_hh + (size_t)n * HDIM + (k0 - INDIM));
    float4 lo = ((const float4*)src)[0];
    float4 hi = ((const float4*)src)[1];
    union { unsigned short us[8]; uint4 v; } o;
    o.us[0] = f2bf(lo.x); o.us[1] = f2bf(lo.y); o.us[2] = f2bf(lo.z); o.us[3] = f2bf(lo.w);
    o.us[4] = f2bf(hi.x); o.us[5] = f2bf(hi.y); o.us[6] = f2bf(hi.z); o.us[7] = f2bf(hi.w);
    *(uint4*)(W + (size_t)np * KDIM + k0) = o.v;
    if (rem == 0) bias[np] = b_ih[n] + b_hh[n];
  }
}

__device__ __forceinline__ void gload_lds16(const void* g, void* l) {
  __builtin_amdgcn_global_load_lds(
      (const __attribute__((address_space(1))) void*)g,
      (__attribute__((address_space(3))) void*)l, 16, 0, 0);
}

// 256x256 tile, BK=64, 8 waves (2Mx4N), 2 LDS buffers (2 x 64KiB).
// m201-style 4-phase/K-tile schedule: each phase = {ds-reads (1 phase ahead)
// | 1 stage slot | barrier | lgkm0 | setprio+16 MFMA | barrier}; one counted
// vmcnt(4) per K-tile (FIFO: forces 4-phase-old A stage landed, keeps newest
// B stages in flight). Row-pair XOR swizzle (T2) on 128B rows.
// Buffer: A[256][64]sw at +0 (32KB), B[256][64]sw at +32768.
// Swizzle: 16B chunk_phys = chunk_log ^ (row & 7) within each 128B row.
__global__ __launch_bounds__(512, 2) void lstm_gemm(
    const unsigned short* __restrict__ A,
    const unsigned short* __restrict__ W,
    const float* __restrict__ bias,
    const float* __restrict__ c,
    float* __restrict__ out) {
  extern __shared__ char smem[];  // 131072 bytes

  const int tid = threadIdx.x;
  const int lane = tid & 63;
  const int wid = tid >> 6;

  // XCD swizzle (R4's, FETCH-verified): xcd owns 2 tm slabs; tn sweeps slowest.
  const int bid = blockIdx.x;              // 512 blocks
  const int local = bid >> 3;
  const int tm = (bid & 7) * 2 + (local & 1);   // 0..15
  const int tn = local >> 1;                    // 0..31

  // ---- staging source decode (inverse swizzle, rule #21) ----
  // Thread stages 16B at region-local P = h*16384 + i*8192 + tid*16.
  // row = h*128 + i*64 + (tid>>3); chunk_log = (tid&7) ^ ((tid>>3)&7).
  const int clog = (tid & 7) ^ ((tid >> 3) & 7);
  const int srow = tid >> 3;  // 0..63
  const unsigned short* pA00 = A + (size_t)(tm * 256 +   0 + srow) * KDIM + clog * 8;
  const unsigned short* pA01 = A + (size_t)(tm * 256 +  64 + srow) * KDIM + clog * 8;
  const unsigned short* pA10 = A + (size_t)(tm * 256 + 128 + srow) * KDIM + clog * 8;
  const unsigned short* pA11 = A + (size_t)(tm * 256 + 192 + srow) * KDIM + clog * 8;
  const unsigned short* pB00 = W + (size_t)(tn * 256 +   0 + srow) * KDIM + clog * 8;
  const unsigned short* pB01 = W + (size_t)(tn * 256 +  64 + srow) * KDIM + clog * 8;
  const unsigned short* pB10 = W + (size_t)(tn * 256 + 128 + srow) * KDIM + clog * 8;
  const unsigned short* pB11 = W + (size_t)(tn * 256 + 192 + srow) * KDIM + clog * 8;
  const int dwid = wid * 1024;

  // ---- ds_read per-lane constants (swizzled) ----
  const int fr = lane & 15;
  const int fq = lane >> 4;
  const int wr = wid >> 2;    // 0..1 (M rows)
  const int wc = wid & 3;     // 0..3 (N cols)
  int colK[2];
#pragma unroll
  for (int ks = 0; ks < 2; ++ks) colK[ks] = (((ks * 4 + fq) ^ (fr & 7)) << 4);
  const int abase = wr * 16384 + fr * 128;
  const int bbase = 32768 + wc * 8192 + fr * 128;

  f32x4 acc[8][4] = {};
  short8 fa[4][2], fb0[2][2], fb1[2][2];

  char* cb = smem;
  char* nb = smem + 65536;

#define BAR __builtin_amdgcn_s_barrier()
#define LGKM0 asm volatile("s_waitcnt lgkmcnt(0)" ::: "memory")
#define STG_A(DB, T1)                                                        \
  do {                                                                       \
    gload_lds16(pA00 + (size_t)(T1) * 64, (DB) + 0 + dwid);                  \
    gload_lds16(pA01 + (size_t)(T1) * 64, (DB) + 8192 + dwid);               \
    gload_lds16(pA10 + (size_t)(T1) * 64, (DB) + 16384 + dwid);              \
    gload_lds16(pA11 + (size_t)(T1) * 64, (DB) + 24576 + dwid);              \
  } while (0)
#define STG_B_H0(DB, T2)                                                     \
  do {                                                                       \
    gload_lds16(pB00 + (size_t)(T2) * 64, (DB) + 32768 + dwid);              \
    gload_lds16(pB01 + (size_t)(T2) * 64, (DB) + 40960 + dwid);              \
  } while (0)
#define STG_B_H1(DB, T2)                                                     \
  do {                                                                       \
    gload_lds16(pB10 + (size_t)(T2) * 64, (DB) + 49152 + dwid);              \
    gload_lds16(pB11 + (size_t)(T2) * 64, (DB) + 57344 + dwid);              \
  } while (0)
#define READ_FA(MIH)                                                         \
  _Pragma("unroll")                                                          \
  for (int mi = 0; mi < 4; ++mi)                                             \
    _Pragma("unroll")                                                        \
    for (int ks = 0; ks < 2; ++ks)                                           \
      fa[mi][ks] = *(const short8*)(cb + abase + ((MIH)*4 + mi) * 2048 + colK[ks]);
#define READ_FB(DST, NIH)                                                    \
  _Pragma("unroll")                                                          \
  for (int ni = 0; ni < 2; ++ni)                                             \
    _Pragma("unroll")                                                        \
    for (int ks = 0; ks < 2; ++ks)                                           \
      DST[ni][ks] = *(const short8*)(cb + bbase + ((NIH)*2 + ni) * 2048 + colK[ks]);
#define CLUST(FB, MIH, NIH)                                                  \
  do {                                                                       \
    __builtin_amdgcn_s_setprio(1);                                           \
    _Pragma("unroll")                                                        \
    for (int ks = 0; ks < 2; ++ks)                                           \
      _Pragma("unroll")                                                      \
      for (int mi = 0; mi < 4; ++mi)                                         \
        _Pragma("unroll")                                                    \
        for (int ni = 0; ni < 2; ++ni)                                       \
          acc[(MIH)*4 + mi][(NIH)*2 + ni] =                                  \
              __builtin_amdgcn_mfma_f32_16x16x32_bf16(                       \
                  fa[mi][ks], FB[ni][ks], acc[(MIH)*4 + mi][(NIH)*2 + ni],   \
                  0, 0, 0);                                                  \
    __builtin_amdgcn_s_setprio(0);                                           \
  } while (0)

// One K-tile = 4 phases. Reads are current-tile only (1 phase ahead of use).
// Stages: A(T+1)->nb at p0; B(T+2)->cb at p2/p3 (regions barrier-certified free).
#define TILE(T, SA_, SB_, VMSTR)                                             \
  do {                                                                       \
    /* p0 */                                                                 \
    READ_FA(0);                                                              \
    READ_FB(fb0, 0);                                                         \
    if (SA_) STG_A(nb, (T) + 1);                                             \
    BAR; LGKM0; CLUST(fb0, 0, 0); BAR;                                       \
    /* p1 */                                                                 \
    READ_FB(fb1, 1);                                                         \
    BAR; LGKM0; CLUST(fb1, 0, 1); BAR;                                       \
    /* p2 */                                                                 \
    READ_FA(1);                                                              \
    if (SB_) STG_B_H0(cb, (T) + 2);                                          \
    BAR; LGKM0; CLUST(fb0, 1, 0); BAR;                                       \
    /* p3 */                                                                 \
    if (SB_) STG_B_H1(cb, (T) + 2);                                          \
    asm volatile("s_waitcnt vmcnt(" VMSTR ")" ::: "memory");                 \
    BAR; CLUST(fb1, 1, 1); BAR;                                              \
  } while (0)

  // ---- prologue: stage tile0 (cb) + B(1) (nb) ----
  STG_A(cb, 0);
  STG_B_H0(cb, 0); STG_B_H1(cb, 0);
  STG_B_H0(nb, 1); STG_B_H1(nb, 1);
  asm volatile("s_waitcnt vmcnt(4)" ::: "memory");  // tile0 landed; B(1) in flight
  BAR;

  for (int t = 0; t <= 45; ++t) {
    TILE(t, true, true, "4");
    char* tmp = cb; cb = nb; nb = tmp;
  }
  TILE(46, true, false, "0");
  { char* tmp = cb; cb = nb; nb = tmp; }
  TILE(47, false, false, "0");

#undef TILE
#undef CLUST
#undef READ_FB
#undef READ_FA
#undef STG_B_H1
#undef STG_B_H0
#undef STG_A

  // ---- fused LSTM epilogue ----
  // Wave owns 128x64 gates (rows tm*256+wr*128+mi*16+[0,16), cols 16 j x 4 gates).
  // Wave-private LDS bounce, stride 68 floats (4608 B/wave).
  const int jw = fr;
  const int jg = tn * 64 + wc * 16 + jw;   // global j in [0,2048)
  const f32x4 bi = *(const f32x4*)(bias + tn * 256 + wc * 64 + jw * 4);
  float* ep = (float*)smem + wid * 1152;

#pragma unroll
  for (int mi = 0; mi < 8; ++mi) {
#pragma unroll
    for (int ni = 0; ni < 4; ++ni)
#pragma unroll
      for (int r = 0; r < 4; ++r)
        ep[(fq * 4 + r) * 68 + ni * 16 + fr] = acc[mi][ni][r];
    LGKM0;
#pragma unroll
    for (int t4 = 0; t4 < 4; ++t4) {
      const int row = fq + t4 * 4;         // 0..15
      f32x4 g4 = *(const f32x4*)(ep + row * 68 + jw * 4);
      const float f_in = g4[0] + bi[0];
      const float i_in = g4[1] + bi[1];
      const float ic_in = g4[2] + bi[2];
      const float o_in = g4[3] + bi[3];
      const float ft = sigmoidf_(f_in);
      const float it = sigmoidf_(i_in);
      const float ics = __sinf(ic_in);
      const int mg = tm * 256 + wr * 128 + mi * 16 + row;
      const float cv = c[(size_t)mg * HDIM + jg];
      const float ct = cv * ft + ics * it;
      const float ot = sigmoidf_(o_in);
      const float ht = ot * __sinf(ct);
      out[(size_t)mg * HDIM + jg] = ht;
      out[OUT_HALF + (size_t)mg * HDIM + jg] = ct;
    }
    LGKM0;
  }
#undef LGKM0
#undef BAR
}

extern "C" void kernel_launch(void* const* d_in, const int* in_sizes, int n_in,
                              void* d_out, int out_size, void* d_ws, size_t ws_size,
                              hipStream_t stream) {
  const float* x    = (const float*)d_in[0];
  const float* h    = (const float*)d_in[1];
  const float* c    = (const float*)d_in[2];
  const float* w_ih = (const float*)d_in[3];
  const float* w_hh = (const float*)d_in[4];
  const float* b_ih = (const float*)d_in[5];
  const float* b_hh = (const float*)d_in[6];
  float* out = (float*)d_out;

  char* ws = (char*)d_ws;
  unsigned short* Abf = (unsigned short*)ws;                       // 25,165,824 B
  unsigned short* Wbf = (unsigned short*)(ws + 25165824);          // 50,331,648 B
  float* bias = (float*)(ws + 25165824 + 50331648);                // 32,768 B

  hipFuncSetAttribute((const void*)lstm_gemm,
                      hipFuncAttributeMaxDynamicSharedMemorySize, 131072);

  pack_all<<<18432, 256, 0, stream>>>(x, h, w_ih, w_hh, b_ih, b_hh, Abf, Wbf, bias);
  lstm_gemm<<<512, 512, 131072, stream>>>(Abf, Wbf, bias, c, out);
}